// Round 3
// baseline (668.770 us; speedup 1.0000x reference)
//
#include <hip/hip_runtime.h>

// ---------------- problem constants ----------------
#define N_NODES 50000
#define N_EDGES 800000
#define P_PERT  4
#define NTOT    (P_PERT * N_NODES)   // 200000
#define HDIM    64
#define NGRAPH  512
#define NCLASS  10
#define BN_EPS  1e-5f
#define SCAN_BLOCKS ((N_NODES + 255) / 256)   // 196
#define BN_SLICES 64
#define SAH_STRIDE 72  // halves; 144B rows, 16B-aligned frag reads, 2-way bank alias max
#define SC_STRIDE 72   // halves
#define ZERO_FLOATS 297120          // 1188480 bytes zeroed at ws start

typedef _Float16 half4 __attribute__((ext_vector_type(4)));
typedef _Float16 f16x8 __attribute__((ext_vector_type(8)));
typedef float    f32x4 __attribute__((ext_vector_type(4)));

// R18 (this round): hwh is re-laid-out as 8 XCD-resident partitions:
//   hwh2[part][node][32 halves], part = p*2 + feature_half  (3.2 MB each < 4 MiB L2)
// gather blocks pin part = blockIdx&7 (round-robin blockIdx->XCD). Each XCD's
// hwh working set drops 25.6 MB -> 3.2 MB (fully L2-resident), killing the
// 8x-XCD compulsory re-fetch that made the old 188 MB FETCH floor.
// dinv[s] is folded into hwh at GEMM-write time so csr is ushort src-only
// (12.8 MB total across 8 XCDs vs 51.2 MB as int2).
// R17 lesson: NO device-scope fences in the gather (kills per-XCD L2, 3.5->0.83 TB/s).
// R13 lesson: node records must be alignment-friendly: 64B granules, 4096-aligned base.
// R11 lesson: sBatch LDS staging diverged post-timing; batch[] via registers ok.

// ---------------- CSR build ----------------

__global__ void count_kernel(const int* __restrict__ ei, int* __restrict__ cnt) {
    int j = blockIdx.x * blockDim.x + threadIdx.x;
    if (j >= N_EDGES) return;
    atomicAdd(&cnt[ei[N_EDGES + j]], 1);
}

__global__ void scan_reduce(const int* __restrict__ cnt, int* __restrict__ bsum,
                            float* __restrict__ dinv) {
    __shared__ int sdata[256];
    int i = blockIdx.x * 256 + threadIdx.x;
    int v = (i < N_NODES) ? cnt[i] : 0;
    if (i < N_NODES) dinv[i] = rsqrtf((float)v + 1.0f);
    sdata[threadIdx.x] = v;
    __syncthreads();
    for (int off = 128; off > 0; off >>= 1) {
        if (threadIdx.x < off) sdata[threadIdx.x] += sdata[threadIdx.x + off];
        __syncthreads();
    }
    if (threadIdx.x == 0) bsum[blockIdx.x] = sdata[0];
}

__global__ void scan_tops(const int* __restrict__ bsum, int* __restrict__ boff,
                          int* __restrict__ rowptr) {
    __shared__ int sdata[256];
    int t = threadIdx.x;
    int v = (t < SCAN_BLOCKS) ? bsum[t] : 0;
    sdata[t] = v;
    __syncthreads();
    for (int off = 1; off < 256; off <<= 1) {
        int tmp = (t >= off) ? sdata[t - off] : 0;
        __syncthreads();
        sdata[t] += tmp;
        __syncthreads();
    }
    if (t < SCAN_BLOCKS) boff[t] = sdata[t] - v;
    if (t == 255) rowptr[N_NODES] = sdata[255];
}

__global__ void scan_write(const int* __restrict__ cnt, const int* __restrict__ boff,
                           int* __restrict__ rowptr) {
    __shared__ int sdata[256];
    int i = blockIdx.x * 256 + threadIdx.x;
    int v = (i < N_NODES) ? cnt[i] : 0;
    sdata[threadIdx.x] = v;
    __syncthreads();
    for (int off = 1; off < 256; off <<= 1) {
        int tmp = (threadIdx.x >= off) ? sdata[threadIdx.x - off] : 0;
        __syncthreads();
        sdata[threadIdx.x] += tmp;
        __syncthreads();
    }
    if (i < N_NODES) rowptr[i] = boff[blockIdx.x] + sdata[threadIdx.x] - v;
}

// csr: src index only (ushort; N=50000 < 65536). dinv[s] is pre-folded into hwh2.
__global__ void fill_kernel(const int* __restrict__ ei, const int* __restrict__ rowptr,
                            int* __restrict__ cursor, unsigned short* __restrict__ csr) {
    int j = blockIdx.x * blockDim.x + threadIdx.x;
    if (j >= N_EDGES) return;
    int s = ei[j], d = ei[N_EDGES + j];
    int pos = rowptr[d] + atomicAdd(&cursor[d], 1);
    csr[pos] = (unsigned short)s;
}

// repack conv_w into B-fragment order (fp16) AND zero the ws accumulator region
__global__ void wpack_zero_kernel(const float* __restrict__ W, _Float16* __restrict__ wpack,
                                  float* __restrict__ zreg) {
    int idx = blockIdx.x * 256 + threadIdx.x;
    if (idx < 4 * 4096) {
        int e = idx & 4095;
        int j = e & 7;
        int lane = (e >> 3) & 63;
        int ntkh = e >> 9;
        int kh = ntkh >> 2, nt = ntkh & 3;
        int m = lane & 15, quad = lane >> 4;
        wpack[idx] = (_Float16)W[(idx >> 12) * 4096 + (kh * 32 + quad * 8 + j) * 64 + nt * 16 + m];
    }
    for (int i = idx; i < ZERO_FLOATS; i += gridDim.x * 256) zreg[i] = 0.0f;
}

// reduce 64 BN slices + gamma/beta -> bnss = {scale[64], shift[64]} (once/layer)
__global__ void bn_reduce(const float* __restrict__ bn, const float* __restrict__ gamma,
                          const float* __restrict__ beta, float* __restrict__ bnss) {
    int f = threadIdx.x;
    if (f >= 64) return;
    float su = 0.0f, sq = 0.0f;
    for (int s = 0; s < BN_SLICES; ++s) {
        su += bn[s * 128 + f];
        sq += bn[s * 128 + 64 + f];
    }
    const float inv_n = 1.0f / (float)NTOT;
    float mu = su * inv_n;
    float var = sq * inv_n - mu * mu;
    float sc = gamma[f] * rsqrtf(var + BN_EPS);
    bnss[f] = sc;
    bnss[64 + f] = beta[f] - mu * sc;
}

// ---------------- fused GEMM (MFMA, packed W) ----------------
// Writes hwh2[part][v][32] with dinv[v] folded in (part = p*2 + feature_half).
template <int LAYER0>
__global__ __launch_bounds__(256) void gemm_fused(const void* __restrict__ srcv,
        const int* __restrict__ mask, const float* __restrict__ bnss,
        const int* __restrict__ batch, const _Float16* __restrict__ wpack,
        const float* __restrict__ dinv, _Float16* __restrict__ hwh,
        float* __restrict__ pooled) {
    __shared__ _Float16 sAh[64 * SAH_STRIDE];
    __shared__ _Float16 sC[64 * SC_STRIDE];
    int tid = threadIdx.x;
    size_t rowbase = (size_t)blockIdx.x * 64;
    int lane = tid & 63;
    int wv = tid >> 6;
    // batch values for this wave's 16 pooled rows: wave-uniform scalar loads,
    // issued up-front so latency hides under A-staging + MFMA.
    int bg[16];
#pragma unroll
    for (int rr = 0; rr < 16; ++rr)
        bg[rr] = batch[(int)((rowbase + wv * 16 + rr) % N_NODES)];
    // B frags: coalesced f16x8 loads from packed W (16 KB, L2-hot)
    const f16x8* wp = (const f16x8*)wpack;
    f16x8 bfrag[2][4];
#pragma unroll
    for (int kh = 0; kh < 2; ++kh)
#pragma unroll
        for (int nt = 0; nt < 4; ++nt)
            bfrag[kh][nt] = wp[(kh * 4 + nt) * 64 + lane];
    // A staging (fp16): thread -> (row r0 + it*16, features f4..f4+3)
    int r0 = tid >> 4;
    int f4l = (tid & 15) * 4;
    float4 sc4, sh4;
    if (!LAYER0) {
        sc4 = *(const float4*)&bnss[f4l];
        sh4 = *(const float4*)&bnss[64 + f4l];
    }
#pragma unroll
    for (int it = 0; it < 4; ++it) {
        int r = r0 + it * 16;
        int grow = (int)rowbase + r;
        float4 val;
        if (LAYER0) {
            const float* src = (const float*)srcv;
            int p = grow / N_NODES, v = grow - p * N_NODES;
            if (mask[p * N_NODES + v]) {
                val = make_float4(0.f, 0.f, 0.f, 0.f);
            } else {
                val = *(const float4*)&src[(size_t)v * HDIM + f4l];
            }
        } else {
            const _Float16* src = (const _Float16*)srcv;
            half4 hv = *(const half4*)&src[(size_t)grow * HDIM + f4l];
            val.x = fmaxf((float)hv.x * sc4.x + sh4.x, 0.0f);
            val.y = fmaxf((float)hv.y * sc4.y + sh4.y, 0.0f);
            val.z = fmaxf((float)hv.z * sc4.z + sh4.z, 0.0f);
            val.w = fmaxf((float)hv.w * sc4.w + sh4.w, 0.0f);
        }
        half4 hv4 = {(_Float16)val.x, (_Float16)val.y, (_Float16)val.z, (_Float16)val.w};
        *(half4*)&sAh[r * SAH_STRIDE + f4l] = hv4;
    }
    __syncthreads();
    // MFMA: wave wv owns rows wv*16..wv*16+15; A-frag = one ds_read_b128 per kh
    int m = lane & 15;
    int quad = lane >> 4;
    f32x4 acc4[4];
#pragma unroll
    for (int nt = 0; nt < 4; ++nt) acc4[nt] = (f32x4){0.f, 0.f, 0.f, 0.f};
#pragma unroll
    for (int kh = 0; kh < 2; ++kh) {
        f16x8 a = *(const f16x8*)&sAh[(wv * 16 + m) * SAH_STRIDE + kh * 32 + quad * 8];
#pragma unroll
        for (int nt = 0; nt < 4; ++nt)
            acc4[nt] = __builtin_amdgcn_mfma_f32_16x16x32_f16(a, bfrag[kh][nt], acc4[nt], 0, 0, 0);
    }
    // C frag layout: col = nt*16+m, row(in 16-tile) = quad*4+reg -> stage to sC
    // with dinv[v] folded in (gather consumes dinv_s-scaled messages).
#pragma unroll
    for (int reg = 0; reg < 4; ++reg) {
        int crow = wv * 16 + quad * 4 + reg;
        int growc = (int)rowbase + crow;
        int vc = growc % N_NODES;
        float dsc = dinv[vc];
#pragma unroll
        for (int nt = 0; nt < 4; ++nt)
            sC[crow * SC_STRIDE + nt * 16 + m] = (_Float16)(acc4[nt][reg] * dsc);
    }
    __syncthreads();
    // coalesced store first: thread -> row tid>>2, 16B chunk (tid&3) into both
    // feature-half partitions (64B node granules, contiguous per part).
    {
        int r = tid >> 2, c = tid & 3;
        int grow = (int)rowbase + r;
        int p = grow / N_NODES, v = grow - p * N_NODES;
        _Float16* dst0 = &hwh[((size_t)(p * 2 + 0) * N_NODES + (size_t)v) * 32];
        _Float16* dst1 = &hwh[((size_t)(p * 2 + 1) * N_NODES + (size_t)v) * 32];
        *(f16x8*)&dst0[c * 8] = *(f16x8*)&sC[r * SC_STRIDE + c * 8];
        *(f16x8*)&dst1[c * 8] = *(f16x8*)&sC[r * SC_STRIDE + (c + 4) * 8];
    }
    // pooling last (overlaps store drain): wave pools its 16 rows from sAh
    {
        int f = lane;
        int curg = -1;
        float acc = 0.0f;
#pragma unroll
        for (int rr = 0; rr < 16; ++rr) {
            int g = bg[rr];
            if (g != curg) {
                if (curg >= 0) atomicAdd(&pooled[curg * HDIM + f], acc * (1.0f / P_PERT));
                curg = g;
                acc = 0.0f;
            }
            acc += (float)sAh[(wv * 16 + rr) * SAH_STRIDE + f];
        }
        atomicAdd(&pooled[curg * HDIM + f], acc * (1.0f / P_PERT));
    }
}

// ---------------- XCD-partitioned gather ----------------
// part = blockIdx&7 -> XCD (round-robin dispatch); each part's hwh2 sub-array
// is 3.2 MB (L2-resident). Wave = 2 nodes x 4 edge-slots x 8 feature-lanes;
// 8 edge-slots per iteration (tail-masked), 2-level shfl_xor reduction.
__global__ __launch_bounds__(256) void gather_bn(const _Float16* __restrict__ hwh2,
        const int* __restrict__ rowptr, const unsigned short* __restrict__ csr,
        const float* __restrict__ dinv, const float* __restrict__ b,
        _Float16* __restrict__ h, float* __restrict__ bn) {
    __shared__ float lsum[4][2][8][4];
    __shared__ float lssq[4][2][8][4];
    int tid = threadIdx.x;
    int lane = tid & 63;
    int wv = tid >> 6;
    int part = blockIdx.x & 7;          // -> XCD
    int g = blockIdx.x >> 3;            // 0..6249
    int p = part >> 1, fh = part & 1;
    const _Float16* src = hwh2 + (size_t)part * ((size_t)N_NODES * 32);
    int nsel = lane >> 5;               // node select within wave
    int e4 = (lane >> 3) & 3;           // edge slot
    int f8 = lane & 7;                  // feature quad within 32-half part
    int v = g * 8 + wv * 2 + nsel;
    int kb = rowptr[v], ke = rowptr[v + 1];
    float di = dinv[v];
    float4 b4 = *(const float4*)&b[fh * 32 + f8 * 4];
    half4 sv = *(const half4*)&src[(size_t)v * 32 + f8 * 4];   // self term (post-reduce)
    float4 acc = make_float4(0.f, 0.f, 0.f, 0.f);
    int k = kb + e4;
    while (__any(k < ke)) {
        bool a0 = k < ke, a1 = (k + 4) < ke;
        int s0 = 0, s1 = 0;
        if (a0) s0 = csr[k];
        if (a1) s1 = csr[k + 4];
        half4 m0 = (half4)(_Float16)0.0f;
        half4 m1 = (half4)(_Float16)0.0f;
        if (a0) m0 = *(const half4*)&src[(size_t)s0 * 32 + f8 * 4];
        if (a1) m1 = *(const half4*)&src[(size_t)s1 * 32 + f8 * 4];
        acc.x += (float)m0.x + (float)m1.x;
        acc.y += (float)m0.y + (float)m1.y;
        acc.z += (float)m0.z + (float)m1.z;
        acc.w += (float)m0.w + (float)m1.w;
        k += 8;
    }
    // reduce across the 4 edge slots (lane bits 3,4); both nodes in parallel
#pragma unroll
    for (int d = 8; d <= 16; d <<= 1) {
        acc.x += __shfl_xor(acc.x, d);
        acc.y += __shfl_xor(acc.y, d);
        acc.z += __shfl_xor(acc.z, d);
        acc.w += __shfl_xor(acc.w, d);
    }
    if (e4 == 0) {
        float4 hv;
        hv.x = fmaf(di, acc.x + (float)sv.x, b4.x);
        hv.y = fmaf(di, acc.y + (float)sv.y, b4.y);
        hv.z = fmaf(di, acc.z + (float)sv.z, b4.z);
        hv.w = fmaf(di, acc.w + (float)sv.w, b4.w);
        half4 hh = {(_Float16)hv.x, (_Float16)hv.y, (_Float16)hv.z, (_Float16)hv.w};
        // nontemporal: consumed only by the next dispatch; keep hwh2 L2-resident
        __builtin_nontemporal_store(hh,
            (half4*)&h[((size_t)p * N_NODES + (size_t)v) * HDIM + fh * 32 + f8 * 4]);
        lsum[wv][nsel][f8][0] = hv.x; lsum[wv][nsel][f8][1] = hv.y;
        lsum[wv][nsel][f8][2] = hv.z; lsum[wv][nsel][f8][3] = hv.w;
        lssq[wv][nsel][f8][0] = hv.x * hv.x; lssq[wv][nsel][f8][1] = hv.y * hv.y;
        lssq[wv][nsel][f8][2] = hv.z * hv.z; lssq[wv][nsel][f8][3] = hv.w * hv.w;
    }
    __syncthreads();
    if (tid < 32) {
        float s = 0.f, q = 0.f;
#pragma unroll
        for (int w = 0; w < 4; ++w)
#pragma unroll
            for (int n = 0; n < 2; ++n) {
                s += lsum[w][n][tid >> 2][tid & 3];
                q += lssq[w][n][tid >> 2][tid & 3];
            }
        float* bns = bn + (blockIdx.x & (BN_SLICES - 1)) * 128;
        int f = fh * 32 + tid;
        atomicAdd(&bns[f], s);
        atomicAdd(&bns[64 + f], q);
    }
}

// pool of last layer's activation using precomputed scale/shift
__global__ void final_pool(const _Float16* __restrict__ h, const float* __restrict__ bnss,
                           const int* __restrict__ batch, float* __restrict__ pooled) {
    int t = blockIdx.x * blockDim.x + threadIdx.x;
    if (t >= N_NODES * HDIM) return;
    int v = t >> 6, f = t & 63;
    float sc = bnss[f], sh = bnss[64 + f];
    float s = 0.0f;
#pragma unroll
    for (int p = 0; p < P_PERT; ++p) {
        size_t idx = ((size_t)(p * N_NODES + v)) * HDIM + f;
        s += fmaxf((float)h[idx] * sc + sh, 0.0f);
    }
    atomicAdd(&pooled[batch[v] * HDIM + f], s * (1.0f / P_PERT));
}

// y[g][c] = sum_i pooled_i[g] @ fc_w[i][:,c] + fc_b[i][c]; out = log_softmax(y)
__global__ void head_kernel(const float* __restrict__ pooled, const float* __restrict__ fcw,
                            const float* __restrict__ fcb, float* __restrict__ out) {
    int g = blockIdx.x;
    __shared__ float y[NCLASS];
    __shared__ float lse;
    int c = threadIdx.x;
    if (c < NCLASS) {
        float acc = 0.0f;
        for (int i = 0; i < 5; ++i) {
            acc += fcb[i * NCLASS + c];
            const float* pr = &pooled[((size_t)i * NGRAPH + g) * HDIM];
            const float* w = &fcw[i * HDIM * NCLASS + c];
            for (int k = 0; k < HDIM; ++k) acc += pr[k] * w[k * NCLASS];
        }
        y[c] = acc;
    }
    __syncthreads();
    if (threadIdx.x == 0) {
        float m = y[0];
        for (int i = 1; i < NCLASS; ++i) m = fmaxf(m, y[i]);
        float s = 0.0f;
        for (int i = 0; i < NCLASS; ++i) s += expf(y[i] - m);
        lse = m + logf(s);
    }
    __syncthreads();
    if (c < NCLASS) out[g * NCLASS + c] = y[c] - lse;
}

// ---------------- launch ----------------
extern "C" void kernel_launch(void* const* d_in, const int* in_sizes, int n_in,
                              void* d_out, int out_size, void* d_ws, size_t ws_size,
                              hipStream_t stream) {
    const float* x      = (const float*)d_in[0];
    const int*   ei     = (const int*)d_in[1];
    const int*   batch  = (const int*)d_in[2];
    const int*   mask   = (const int*)d_in[3];
    const float* conv_w = (const float*)d_in[4];
    const float* conv_b = (const float*)d_in[5];
    const float* gamma  = (const float*)d_in[6];
    const float* beta   = (const float*)d_in[7];
    const float* fcw    = (const float*)d_in[8];
    const float* fcb    = (const float*)d_in[9];
    float* out = (float*)d_out;

    char* ws = (char*)d_ws;
    // --- contiguous zeroed region [0, 1188480) (ZERO_FLOATS*4) ---
    int*      cnt     = (int*)(ws + 0);             // N ints
    int*      cursor  = (int*)(ws + 200000);        // N ints
    float*    pooled  = (float*)(ws + 400000);      // 5*512*64 f -> ends 1055360
    float*    bn      = (float*)(ws + 1055360);     // 4*64*128 f -> ends 1186432
    float*    bnss    = (float*)(ws + 1186432);     // 4*128 f -> ends 1188480
    // --- rest; h/hwh 4096-aligned ---
    int*      rowptr  = (int*)(ws + 1188480);       // N+1 ints -> ends 1388484
    float*    dinv    = (float*)(ws + 1388484);     // N f -> ends 1588484
    unsigned short* csr = (unsigned short*)(ws + 1588484); // E u16 -> ends 3188484
    _Float16* h       = (_Float16*)(ws + 3190784);  // 4096-aligned; 25.6 MB
    _Float16* hwh     = (_Float16*)(ws + 28790784); // 4096-aligned; 8 parts x 3.2 MB
    int*      bsum    = (int*)(ws + 54390784);      // 256 ints
    int*      boff    = (int*)(ws + 54391808);      // 256 ints
    _Float16* wpack   = (_Float16*)(ws + 54392832); // 4*4096 fp16 (32 KB)

    wpack_zero_kernel<<<512, 256, 0, stream>>>(conv_w, wpack, (float*)ws);
    count_kernel<<<(N_EDGES + 255) / 256, 256, 0, stream>>>(ei, cnt);
    scan_reduce<<<SCAN_BLOCKS, 256, 0, stream>>>(cnt, bsum, dinv);
    scan_tops<<<1, 256, 0, stream>>>(bsum, boff, rowptr);
    scan_write<<<SCAN_BLOCKS, 256, 0, stream>>>(cnt, boff, rowptr);
    fill_kernel<<<(N_EDGES + 255) / 256, 256, 0, stream>>>(ei, rowptr, cursor, csr);

    const int gather_grid = N_NODES;   // 50000 blocks = 8 parts x 6250 groups
    for (int i = 0; i < 4; ++i) {
        float* bni = bn + i * BN_SLICES * 128;
        if (i == 0)
            gemm_fused<1><<<NTOT / 64, 256, 0, stream>>>(x, mask, nullptr,
                                                         batch, wpack, dinv, hwh, pooled);
        else
            gemm_fused<0><<<NTOT / 64, 256, 0, stream>>>(h, nullptr, bnss + (i - 1) * 128,
                                                         batch, wpack + (size_t)i * 4096,
                                                         dinv, hwh,
                                                         pooled + (size_t)i * NGRAPH * HDIM);
        gather_bn<<<gather_grid, 256, 0, stream>>>(hwh, rowptr, csr, dinv,
                                                   conv_b + i * HDIM, h, bni);
        bn_reduce<<<1, 64, 0, stream>>>(bni, gamma + i * HDIM, beta + i * HDIM,
                                        bnss + i * 128);
    }
    final_pool<<<(N_NODES * HDIM + 255) / 256, 256, 0, stream>>>(
        h, bnss + 3 * 128, batch, pooled + (size_t)4 * NGRAPH * HDIM);
    head_kernel<<<NGRAPH, 64, 0, stream>>>(pooled, fcw, fcb, out);
}

// Round 5
// 492.470 us; speedup vs baseline: 1.3580x; 1.3580x over previous
//
#include <hip/hip_runtime.h>

// ---------------- problem constants ----------------
#define N_NODES 50000
#define N_EDGES 800000
#define P_PERT  4
#define NTOT    (P_PERT * N_NODES)   // 200000
#define HDIM    64
#define NGRAPH  512
#define NCLASS  10
#define BN_EPS  1e-5f
#define SCAN_BLOCKS ((N_NODES + 255) / 256)   // 196
#define BN_SLICES 64
#define SAH_STRIDE 72  // halves; 144B rows, 16B-aligned frag reads, 2-way bank alias max
#define SC_STRIDE 72   // halves
#define ZERO_FLOATS 297120          // 1188480 bytes zeroed at ws start
#define PSTRIDE ((size_t)(N_NODES + 1) * 32)   // halves per part (+1 zeroed dummy node)
#define GATHER_BLOCKS (((N_NODES + 31) / 32) * 8)  // 1563 groups x 8 parts = 12504

typedef _Float16 half4 __attribute__((ext_vector_type(4)));
typedef _Float16 f16x8 __attribute__((ext_vector_type(8)));
typedef float    f32x4 __attribute__((ext_vector_type(4)));
typedef unsigned short u16x8 __attribute__((ext_vector_type(8)));

// R18: hwh as 8 XCD-resident partitions [part][node][32 halves], part = p*2+fh
// (3.2 MB each < 4 MiB per-XCD L2); gather pins part = blockIdx&7. VERIFIED R3:
// FETCH 188 -> 20.6 MB. dinv[s] folded into hwh at GEMM-write; csr = ushort src.
// R19 (this round): R3 showed gather went latency-bound (105 us, VALU 53%,
// HBM 7%): 2-deep conditional loads + __any-loop killed MLP. Rewrite: wave =
// 8 nodes x 8 flanes, node-per-lane edge walk, edge lists PADDED to x8 with a
// zeroed dummy node -> branchless 9-deep load pipeline (1 u16x8 csr + 8 half4),
// no per-edge weights, no cross-lane edge reduce. BN via 3-level shfl_xor.
// R17 lesson: NO device-scope fences in the gather (kills per-XCD L2).
// R13 lesson: 64B node granules, 4096-aligned bases.

// ---------------- CSR build ----------------

__global__ void count_kernel(const int* __restrict__ ei, int* __restrict__ cnt) {
    int j = blockIdx.x * blockDim.x + threadIdx.x;
    if (j >= N_EDGES) return;
    atomicAdd(&cnt[ei[N_EDGES + j]], 1);
}

// scans PADDED counts ((cnt+7)&~7) so every node's list is a multiple of 8;
// dinv still uses the raw count.
__global__ void scan_reduce(const int* __restrict__ cnt, int* __restrict__ bsum,
                            float* __restrict__ dinv) {
    __shared__ int sdata[256];
    int i = blockIdx.x * 256 + threadIdx.x;
    int v = (i < N_NODES) ? cnt[i] : 0;
    if (i < N_NODES) dinv[i] = rsqrtf((float)v + 1.0f);
    sdata[threadIdx.x] = (v + 7) & ~7;
    __syncthreads();
    for (int off = 128; off > 0; off >>= 1) {
        if (threadIdx.x < off) sdata[threadIdx.x] += sdata[threadIdx.x + off];
        __syncthreads();
    }
    if (threadIdx.x == 0) bsum[blockIdx.x] = sdata[0];
}

__global__ void scan_tops(const int* __restrict__ bsum, int* __restrict__ boff,
                          int* __restrict__ rowptr) {
    __shared__ int sdata[256];
    int t = threadIdx.x;
    int v = (t < SCAN_BLOCKS) ? bsum[t] : 0;
    sdata[t] = v;
    __syncthreads();
    for (int off = 1; off < 256; off <<= 1) {
        int tmp = (t >= off) ? sdata[t - off] : 0;
        __syncthreads();
        sdata[t] += tmp;
        __syncthreads();
    }
    if (t < SCAN_BLOCKS) boff[t] = sdata[t] - v;
    if (t == 255) rowptr[N_NODES] = sdata[255];
}

__global__ void scan_write(const int* __restrict__ cnt, const int* __restrict__ boff,
                           int* __restrict__ rowptr) {
    __shared__ int sdata[256];
    int i = blockIdx.x * 256 + threadIdx.x;
    int v = (i < N_NODES) ? ((cnt[i] + 7) & ~7) : 0;
    sdata[threadIdx.x] = v;
    __syncthreads();
    for (int off = 1; off < 256; off <<= 1) {
        int tmp = (threadIdx.x >= off) ? sdata[threadIdx.x - off] : 0;
        __syncthreads();
        sdata[threadIdx.x] += tmp;
        __syncthreads();
    }
    if (i < N_NODES) rowptr[i] = boff[blockIdx.x] + sdata[threadIdx.x] - v;
}

// csr: src index only (ushort). Real entries [rowptr[d], rowptr[d]+cnt[d]).
__global__ void fill_kernel(const int* __restrict__ ei, const int* __restrict__ rowptr,
                            int* __restrict__ cursor, unsigned short* __restrict__ csr) {
    int j = blockIdx.x * blockDim.x + threadIdx.x;
    if (j >= N_EDGES) return;
    int s = ei[j], d = ei[N_EDGES + j];
    int pos = rowptr[d] + atomicAdd(&cursor[d], 1);
    csr[pos] = (unsigned short)s;
}

// fill pad slots [cnt, (cnt+7)&~7) with the dummy node index (zeroed record)
__global__ void pad_kernel(const int* __restrict__ cnt, const int* __restrict__ rowptr,
                           unsigned short* __restrict__ csr) {
    int v = blockIdx.x * 256 + threadIdx.x;
    if (v >= N_NODES) return;
    int c = cnt[v], cp = (c + 7) & ~7, base = rowptr[v];
    for (int j = c; j < cp; ++j) csr[base + j] = (unsigned short)N_NODES;
}

// repack conv_w into B-fragment order (fp16), zero ws accumulators, zero the
// 8 dummy node records in hwh2.
__global__ void wpack_zero_kernel(const float* __restrict__ W, _Float16* __restrict__ wpack,
                                  float* __restrict__ zreg, _Float16* __restrict__ hwh2) {
    int idx = blockIdx.x * 256 + threadIdx.x;
    if (idx < 4 * 4096) {
        int e = idx & 4095;
        int j = e & 7;
        int lane = (e >> 3) & 63;
        int ntkh = e >> 9;
        int kh = ntkh >> 2, nt = ntkh & 3;
        int m = lane & 15, quad = lane >> 4;
        wpack[idx] = (_Float16)W[(idx >> 12) * 4096 + (kh * 32 + quad * 8 + j) * 64 + nt * 16 + m];
    }
    if (idx < 256) {
        hwh2[(size_t)(idx >> 5) * PSTRIDE + (size_t)N_NODES * 32 + (idx & 31)] = (_Float16)0.0f;
    }
    for (int i = idx; i < ZERO_FLOATS; i += gridDim.x * 256) zreg[i] = 0.0f;
}

// reduce 64 BN slices + gamma/beta -> bnss = {scale[64], shift[64]} (once/layer)
__global__ void bn_reduce(const float* __restrict__ bn, const float* __restrict__ gamma,
                          const float* __restrict__ beta, float* __restrict__ bnss) {
    int f = threadIdx.x;
    if (f >= 64) return;
    float su = 0.0f, sq = 0.0f;
    for (int s = 0; s < BN_SLICES; ++s) {
        su += bn[s * 128 + f];
        sq += bn[s * 128 + 64 + f];
    }
    const float inv_n = 1.0f / (float)NTOT;
    float mu = su * inv_n;
    float var = sq * inv_n - mu * mu;
    float sc = gamma[f] * rsqrtf(var + BN_EPS);
    bnss[f] = sc;
    bnss[64 + f] = beta[f] - mu * sc;
}

// ---------------- fused GEMM (MFMA, packed W) ----------------
// Writes hwh2[part][v][32] with dinv[v] folded in (part = p*2 + feature_half).
template <int LAYER0>
__global__ __launch_bounds__(256) void gemm_fused(const void* __restrict__ srcv,
        const int* __restrict__ mask, const float* __restrict__ bnss,
        const int* __restrict__ batch, const _Float16* __restrict__ wpack,
        const float* __restrict__ dinv, _Float16* __restrict__ hwh,
        float* __restrict__ pooled) {
    __shared__ _Float16 sAh[64 * SAH_STRIDE];
    __shared__ _Float16 sC[64 * SC_STRIDE];
    int tid = threadIdx.x;
    size_t rowbase = (size_t)blockIdx.x * 64;
    int lane = tid & 63;
    int wv = tid >> 6;
    // batch values for this wave's 16 pooled rows: wave-uniform scalar loads,
    // issued up-front so latency hides under A-staging + MFMA.
    int bg[16];
#pragma unroll
    for (int rr = 0; rr < 16; ++rr)
        bg[rr] = batch[(int)((rowbase + wv * 16 + rr) % N_NODES)];
    // B frags: coalesced f16x8 loads from packed W (16 KB, L2-hot)
    const f16x8* wp = (const f16x8*)wpack;
    f16x8 bfrag[2][4];
#pragma unroll
    for (int kh = 0; kh < 2; ++kh)
#pragma unroll
        for (int nt = 0; nt < 4; ++nt)
            bfrag[kh][nt] = wp[(kh * 4 + nt) * 64 + lane];
    // A staging (fp16): thread -> (row r0 + it*16, features f4..f4+3)
    int r0 = tid >> 4;
    int f4l = (tid & 15) * 4;
    float4 sc4, sh4;
    if (!LAYER0) {
        sc4 = *(const float4*)&bnss[f4l];
        sh4 = *(const float4*)&bnss[64 + f4l];
    }
#pragma unroll
    for (int it = 0; it < 4; ++it) {
        int r = r0 + it * 16;
        int grow = (int)rowbase + r;
        float4 val;
        if (LAYER0) {
            const float* src = (const float*)srcv;
            int p = grow / N_NODES, v = grow - p * N_NODES;
            if (mask[p * N_NODES + v]) {
                val = make_float4(0.f, 0.f, 0.f, 0.f);
            } else {
                val = *(const float4*)&src[(size_t)v * HDIM + f4l];
            }
        } else {
            const _Float16* src = (const _Float16*)srcv;
            half4 hv = *(const half4*)&src[(size_t)grow * HDIM + f4l];
            val.x = fmaxf((float)hv.x * sc4.x + sh4.x, 0.0f);
            val.y = fmaxf((float)hv.y * sc4.y + sh4.y, 0.0f);
            val.z = fmaxf((float)hv.z * sc4.z + sh4.z, 0.0f);
            val.w = fmaxf((float)hv.w * sc4.w + sh4.w, 0.0f);
        }
        half4 hv4 = {(_Float16)val.x, (_Float16)val.y, (_Float16)val.z, (_Float16)val.w};
        *(half4*)&sAh[r * SAH_STRIDE + f4l] = hv4;
    }
    __syncthreads();
    // MFMA: wave wv owns rows wv*16..wv*16+15; A-frag = one ds_read_b128 per kh
    int m = lane & 15;
    int quad = lane >> 4;
    f32x4 acc4[4];
#pragma unroll
    for (int nt = 0; nt < 4; ++nt) acc4[nt] = (f32x4){0.f, 0.f, 0.f, 0.f};
#pragma unroll
    for (int kh = 0; kh < 2; ++kh) {
        f16x8 a = *(const f16x8*)&sAh[(wv * 16 + m) * SAH_STRIDE + kh * 32 + quad * 8];
#pragma unroll
        for (int nt = 0; nt < 4; ++nt)
            acc4[nt] = __builtin_amdgcn_mfma_f32_16x16x32_f16(a, bfrag[kh][nt], acc4[nt], 0, 0, 0);
    }
    // C frag layout: col = nt*16+m, row(in 16-tile) = quad*4+reg -> stage to sC
    // with dinv[v] folded in (gather consumes dinv_s-scaled messages).
#pragma unroll
    for (int reg = 0; reg < 4; ++reg) {
        int crow = wv * 16 + quad * 4 + reg;
        int growc = (int)rowbase + crow;
        int vc = growc % N_NODES;
        float dsc = dinv[vc];
#pragma unroll
        for (int nt = 0; nt < 4; ++nt)
            sC[crow * SC_STRIDE + nt * 16 + m] = (_Float16)(acc4[nt][reg] * dsc);
    }
    __syncthreads();
    // coalesced store first: thread -> row tid>>2, 16B chunk (tid&3) into both
    // feature-half partitions (64B node granules, contiguous per part).
    {
        int r = tid >> 2, c = tid & 3;
        int grow = (int)rowbase + r;
        int p = grow / N_NODES, v = grow - p * N_NODES;
        _Float16* dst0 = &hwh[(size_t)(p * 2 + 0) * PSTRIDE + (size_t)v * 32];
        _Float16* dst1 = &hwh[(size_t)(p * 2 + 1) * PSTRIDE + (size_t)v * 32];
        *(f16x8*)&dst0[c * 8] = *(f16x8*)&sC[r * SC_STRIDE + c * 8];
        *(f16x8*)&dst1[c * 8] = *(f16x8*)&sC[r * SC_STRIDE + (c + 4) * 8];
    }
    // pooling last (overlaps store drain): wave pools its 16 rows from sAh
    {
        int f = lane;
        int curg = -1;
        float acc = 0.0f;
#pragma unroll
        for (int rr = 0; rr < 16; ++rr) {
            int g = bg[rr];
            if (g != curg) {
                if (curg >= 0) atomicAdd(&pooled[curg * HDIM + f], acc * (1.0f / P_PERT));
                curg = g;
                acc = 0.0f;
            }
            acc += (float)sAh[(wv * 16 + rr) * SAH_STRIDE + f];
        }
        atomicAdd(&pooled[curg * HDIM + f], acc * (1.0f / P_PERT));
    }
}

// ---------------- XCD-partitioned gather, node-per-lane ----------------
// part = blockIdx&7 -> XCD (round-robin dispatch). Wave = 8 nodes x 8 flanes.
// Each lane walks its node's padded edge list 8 edges/iter: 1 u16x8 csr load +
// 8 independent half4 hwh loads (9-deep MLP), branchless (pads hit the zeroed
// dummy record). BN reduce: shfl_xor over the node dimension (bits 3,4,5).
__global__ __launch_bounds__(256) void gather_bn(const _Float16* __restrict__ hwh2,
        const int* __restrict__ rowptr, const unsigned short* __restrict__ csr,
        const float* __restrict__ dinv, const float* __restrict__ b,
        _Float16* __restrict__ h, float* __restrict__ bn) {
    __shared__ float lsum[4][8][4];
    __shared__ float lssq[4][8][4];
    int tid = threadIdx.x;
    int lane = tid & 63;
    int wv = tid >> 6;
    int part = blockIdx.x & 7;          // -> XCD
    int grp = blockIdx.x >> 3;          // node group (32 nodes per block)
    int p = part >> 1, fh = part & 1;
    const _Float16* src = hwh2 + (size_t)part * PSTRIDE;
    int n8 = lane >> 3;                 // node within wave
    int f8 = lane & 7;                  // feature quad within 32-half part
    int v = grp * 32 + wv * 8 + n8;
    bool valid = v < N_NODES;
    int vv = valid ? v : N_NODES;       // dummy row: safe zero reads
    int kb = 0, ke = 0;
    float di = 0.0f;
    if (valid) { kb = rowptr[v]; ke = rowptr[v + 1]; di = dinv[v]; }
    float4 b4 = *(const float4*)&b[fh * 32 + f8 * 4];
    half4 sv = *(const half4*)&src[(size_t)vv * 32 + f8 * 4];   // self term
    float4 acc = make_float4(0.f, 0.f, 0.f, 0.f);
    for (int k = kb; k < ke; k += 8) {
        u16x8 ci = *(const u16x8*)&csr[k];      // 8 src indices, 16B-aligned
        half4 m0 = *(const half4*)&src[(size_t)ci[0] * 32 + f8 * 4];
        half4 m1 = *(const half4*)&src[(size_t)ci[1] * 32 + f8 * 4];
        half4 m2 = *(const half4*)&src[(size_t)ci[2] * 32 + f8 * 4];
        half4 m3 = *(const half4*)&src[(size_t)ci[3] * 32 + f8 * 4];
        half4 m4 = *(const half4*)&src[(size_t)ci[4] * 32 + f8 * 4];
        half4 m5 = *(const half4*)&src[(size_t)ci[5] * 32 + f8 * 4];
        half4 m6 = *(const half4*)&src[(size_t)ci[6] * 32 + f8 * 4];
        half4 m7 = *(const half4*)&src[(size_t)ci[7] * 32 + f8 * 4];
        acc.x += (((float)m0.x + (float)m1.x) + ((float)m2.x + (float)m3.x)) +
                 (((float)m4.x + (float)m5.x) + ((float)m6.x + (float)m7.x));
        acc.y += (((float)m0.y + (float)m1.y) + ((float)m2.y + (float)m3.y)) +
                 (((float)m4.y + (float)m5.y) + ((float)m6.y + (float)m7.y));
        acc.z += (((float)m0.z + (float)m1.z) + ((float)m2.z + (float)m3.z)) +
                 (((float)m4.z + (float)m5.z) + ((float)m6.z + (float)m7.z));
        acc.w += (((float)m0.w + (float)m1.w) + ((float)m2.w + (float)m3.w)) +
                 (((float)m4.w + (float)m5.w) + ((float)m6.w + (float)m7.w));
    }
    float4 hv = make_float4(0.f, 0.f, 0.f, 0.f);
    float4 qv = make_float4(0.f, 0.f, 0.f, 0.f);
    if (valid) {
        hv.x = fmaf(di, acc.x + (float)sv.x, b4.x);
        hv.y = fmaf(di, acc.y + (float)sv.y, b4.y);
        hv.z = fmaf(di, acc.z + (float)sv.z, b4.z);
        hv.w = fmaf(di, acc.w + (float)sv.w, b4.w);
        half4 hh = {(_Float16)hv.x, (_Float16)hv.y, (_Float16)hv.z, (_Float16)hv.w};
        // nontemporal: consumed only by the next dispatch; keep hwh2 L2-resident
        __builtin_nontemporal_store(hh,
            (half4*)&h[((size_t)p * N_NODES + (size_t)v) * HDIM + fh * 32 + f8 * 4]);
        qv.x = hv.x * hv.x; qv.y = hv.y * hv.y;
        qv.z = hv.z * hv.z; qv.w = hv.w * hv.w;
    }
    // reduce across the 8 nodes (lane bits 3,4,5); feature quad preserved
#pragma unroll
    for (int d = 8; d <= 32; d <<= 1) {
        hv.x += __shfl_xor(hv.x, d); hv.y += __shfl_xor(hv.y, d);
        hv.z += __shfl_xor(hv.z, d); hv.w += __shfl_xor(hv.w, d);
        qv.x += __shfl_xor(qv.x, d); qv.y += __shfl_xor(qv.y, d);
        qv.z += __shfl_xor(qv.z, d); qv.w += __shfl_xor(qv.w, d);
    }
    if (lane < 8) {
        lsum[wv][f8][0] = hv.x; lsum[wv][f8][1] = hv.y;
        lsum[wv][f8][2] = hv.z; lsum[wv][f8][3] = hv.w;
        lssq[wv][f8][0] = qv.x; lssq[wv][f8][1] = qv.y;
        lssq[wv][f8][2] = qv.z; lssq[wv][f8][3] = qv.w;
    }
    __syncthreads();
    if (tid < 32) {
        int q = tid >> 2, c = tid & 3;
        float s = lsum[0][q][c] + lsum[1][q][c] + lsum[2][q][c] + lsum[3][q][c];
        float qq = lssq[0][q][c] + lssq[1][q][c] + lssq[2][q][c] + lssq[3][q][c];
        float* bns = bn + (blockIdx.x & (BN_SLICES - 1)) * 128;
        int f = fh * 32 + q * 4 + c;
        atomicAdd(&bns[f], s);
        atomicAdd(&bns[64 + f], qq);
    }
}

// pool of last layer's activation using precomputed scale/shift
__global__ void final_pool(const _Float16* __restrict__ h, const float* __restrict__ bnss,
                           const int* __restrict__ batch, float* __restrict__ pooled) {
    int t = blockIdx.x * blockDim.x + threadIdx.x;
    if (t >= N_NODES * HDIM) return;
    int v = t >> 6, f = t & 63;
    float sc = bnss[f], sh = bnss[64 + f];
    float s = 0.0f;
#pragma unroll
    for (int p = 0; p < P_PERT; ++p) {
        size_t idx = ((size_t)(p * N_NODES + v)) * HDIM + f;
        s += fmaxf((float)h[idx] * sc + sh, 0.0f);
    }
    atomicAdd(&pooled[batch[v] * HDIM + f], s * (1.0f / P_PERT));
}

// y[g][c] = sum_i pooled_i[g] @ fc_w[i][:,c] + fc_b[i][c]; out = log_softmax(y)
__global__ void head_kernel(const float* __restrict__ pooled, const float* __restrict__ fcw,
                            const float* __restrict__ fcb, float* __restrict__ out) {
    int g = blockIdx.x;
    __shared__ float y[NCLASS];
    __shared__ float lse;
    int c = threadIdx.x;
    if (c < NCLASS) {
        float acc = 0.0f;
        for (int i = 0; i < 5; ++i) {
            acc += fcb[i * NCLASS + c];
            const float* pr = &pooled[((size_t)i * NGRAPH + g) * HDIM];
            const float* w = &fcw[i * HDIM * NCLASS + c];
            for (int k = 0; k < HDIM; ++k) acc += pr[k] * w[k * NCLASS];
        }
        y[c] = acc;
    }
    __syncthreads();
    if (threadIdx.x == 0) {
        float m = y[0];
        for (int i = 1; i < NCLASS; ++i) m = fmaxf(m, y[i]);
        float s = 0.0f;
        for (int i = 0; i < NCLASS; ++i) s += expf(y[i] - m);
        lse = m + logf(s);
    }
    __syncthreads();
    if (c < NCLASS) out[g * NCLASS + c] = y[c] - lse;
}

// ---------------- launch ----------------
extern "C" void kernel_launch(void* const* d_in, const int* in_sizes, int n_in,
                              void* d_out, int out_size, void* d_ws, size_t ws_size,
                              hipStream_t stream) {
    const float* x      = (const float*)d_in[0];
    const int*   ei     = (const int*)d_in[1];
    const int*   batch  = (const int*)d_in[2];
    const int*   mask   = (const int*)d_in[3];
    const float* conv_w = (const float*)d_in[4];
    const float* conv_b = (const float*)d_in[5];
    const float* gamma  = (const float*)d_in[6];
    const float* beta   = (const float*)d_in[7];
    const float* fcw    = (const float*)d_in[8];
    const float* fcb    = (const float*)d_in[9];
    float* out = (float*)d_out;

    char* ws = (char*)d_ws;
    // --- contiguous zeroed region [0, 1188480) (ZERO_FLOATS*4) ---
    int*      cnt     = (int*)(ws + 0);             // N ints
    int*      cursor  = (int*)(ws + 200000);        // N ints
    float*    pooled  = (float*)(ws + 400000);      // 5*512*64 f -> ends 1055360
    float*    bn      = (float*)(ws + 1055360);     // 4*64*128 f -> ends 1186432
    float*    bnss    = (float*)(ws + 1186432);     // 4*128 f -> ends 1188480
    // --- rest; h/hwh 4096-aligned, csr 16B-aligned ---
    int*      rowptr  = (int*)(ws + 1188480);       // N+1 ints -> ends 1388484
    float*    dinv    = (float*)(ws + 1388484);     // N f -> ends 1588484
    unsigned short* csr = (unsigned short*)(ws + 1588496); // 1.2M u16 (padded) -> ends 3988496
    _Float16* h       = (_Float16*)(ws + 3989504);  // 4096-aligned; 25.6 MB
    _Float16* hwh     = (_Float16*)(ws + 29589504); // 4096-aligned; 8 x 50001-node parts
    int*      bsum    = (int*)(ws + 55190016);      // 256 ints
    int*      boff    = (int*)(ws + 55191040);      // 256 ints
    _Float16* wpack   = (_Float16*)(ws + 55192064); // 4*4096 fp16 (32 KB)

    wpack_zero_kernel<<<512, 256, 0, stream>>>(conv_w, wpack, (float*)ws, hwh);
    count_kernel<<<(N_EDGES + 255) / 256, 256, 0, stream>>>(ei, cnt);
    scan_reduce<<<SCAN_BLOCKS, 256, 0, stream>>>(cnt, bsum, dinv);
    scan_tops<<<1, 256, 0, stream>>>(bsum, boff, rowptr);
    scan_write<<<SCAN_BLOCKS, 256, 0, stream>>>(cnt, boff, rowptr);
    fill_kernel<<<(N_EDGES + 255) / 256, 256, 0, stream>>>(ei, rowptr, cursor, csr);
    pad_kernel<<<SCAN_BLOCKS, 256, 0, stream>>>(cnt, rowptr, csr);

    for (int i = 0; i < 4; ++i) {
        float* bni = bn + i * BN_SLICES * 128;
        if (i == 0)
            gemm_fused<1><<<NTOT / 64, 256, 0, stream>>>(x, mask, nullptr,
                                                         batch, wpack, dinv, hwh, pooled);
        else
            gemm_fused<0><<<NTOT / 64, 256, 0, stream>>>(h, nullptr, bnss + (i - 1) * 128,
                                                         batch, wpack + (size_t)i * 4096,
                                                         dinv, hwh,
                                                         pooled + (size_t)i * NGRAPH * HDIM);
        gather_bn<<<GATHER_BLOCKS, 256, 0, stream>>>(hwh, rowptr, csr, dinv,
                                                     conv_b + i * HDIM, h, bni);
        bn_reduce<<<1, 64, 0, stream>>>(bni, gamma + i * HDIM, beta + i * HDIM,
                                        bnss + i * 128);
    }
    final_pool<<<(N_NODES * HDIM + 255) / 256, 256, 0, stream>>>(
        h, bnss + 3 * 128, batch, pooled + (size_t)4 * NGRAPH * HDIM);
    head_kernel<<<NGRAPH, 64, 0, stream>>>(pooled, fcw, fcb, out);
}

// Round 11
// 441.535 us; speedup vs baseline: 1.5146x; 1.1154x over previous
//
#include <hip/hip_runtime.h>

// ---------------- problem constants ----------------
#define N_NODES 50000
#define N_EDGES 800000
#define P_PERT  4
#define NTOT    (P_PERT * N_NODES)   // 200000
#define HDIM    64
#define NGRAPH  512
#define NCLASS  10
#define BN_EPS  1e-5f
#define SCAN_BLOCKS ((N_NODES + 255) / 256)   // 196
#define BN_SLICES 64
#define SAH_STRIDE 72  // halves; 144B rows, 16B-aligned frag reads, 2-way bank alias max
#define SC_STRIDE 72   // halves
#define ZERO_FLOATS 297120          // 1188480 bytes zeroed at ws start
#define PSTRIDE ((size_t)(N_NODES + 1) * 32)   // halves per part (+1 zeroed dummy node)
#define GATHER_BLOCKS (((N_NODES + 63) / 64) * 8)  // 782 groups x 8 parts = 6256

typedef _Float16 half4 __attribute__((ext_vector_type(4)));
typedef _Float16 f16x8 __attribute__((ext_vector_type(8)));
typedef float    f32x4 __attribute__((ext_vector_type(4)));
typedef unsigned short u16x8 __attribute__((ext_vector_type(8)));

// R18: hwh as 8 XCD-resident partitions [part][node][32 halves], part = p*2+fh
// (3.2 MB each < 4 MiB per-XCD L2); gather pins part = blockIdx&7. VERIFIED R3:
// FETCH 188 -> 20.6 MB. dinv[s] folded into hwh at GEMM-write; csr = ushort src.
// R19 VERIFIED R5: node-per-lane padded walk -> 57.6 us (105 before), VALU 43%,
// HBM 11% -> still issue/latency-bound, not at any HW ceiling.
// R20 (this round): wave = 16 nodes x 4 flanes (16B f16x8 per lane; halves the
// per-byte address VALU, b128 loads), packed-fp16 tree-sum of each 8-message
// group + one f32 fold per iter (~3x accumulate-VALU cut), csr index load
// software-pipelined (prefetch next iter's u16x8) to break the 2-level
// dependent-load chain. Edge lists remain x8-padded (dummy node 50000).
// R17 lesson: NO device-scope fences in the gather (kills per-XCD L2).
// R13 lesson: 64B node granules, 4096-aligned bases.

// ---------------- CSR build ----------------

__global__ void count_kernel(const int* __restrict__ ei, int* __restrict__ cnt) {
    int j = blockIdx.x * blockDim.x + threadIdx.x;
    if (j >= N_EDGES) return;
    atomicAdd(&cnt[ei[N_EDGES + j]], 1);
}

// scans PADDED counts ((cnt+7)&~7) so every node's list is a multiple of 8;
// dinv still uses the raw count.
__global__ void scan_reduce(const int* __restrict__ cnt, int* __restrict__ bsum,
                            float* __restrict__ dinv) {
    __shared__ int sdata[256];
    int i = blockIdx.x * 256 + threadIdx.x;
    int v = (i < N_NODES) ? cnt[i] : 0;
    if (i < N_NODES) dinv[i] = rsqrtf((float)v + 1.0f);
    sdata[threadIdx.x] = (v + 7) & ~7;
    __syncthreads();
    for (int off = 128; off > 0; off >>= 1) {
        if (threadIdx.x < off) sdata[threadIdx.x] += sdata[threadIdx.x + off];
        __syncthreads();
    }
    if (threadIdx.x == 0) bsum[blockIdx.x] = sdata[0];
}

__global__ void scan_tops(const int* __restrict__ bsum, int* __restrict__ boff,
                          int* __restrict__ rowptr) {
    __shared__ int sdata[256];
    int t = threadIdx.x;
    int v = (t < SCAN_BLOCKS) ? bsum[t] : 0;
    sdata[t] = v;
    __syncthreads();
    for (int off = 1; off < 256; off <<= 1) {
        int tmp = (t >= off) ? sdata[t - off] : 0;
        __syncthreads();
        sdata[t] += tmp;
        __syncthreads();
    }
    if (t < SCAN_BLOCKS) boff[t] = sdata[t] - v;
    if (t == 255) rowptr[N_NODES] = sdata[255];
}

__global__ void scan_write(const int* __restrict__ cnt, const int* __restrict__ boff,
                           int* __restrict__ rowptr) {
    __shared__ int sdata[256];
    int i = blockIdx.x * 256 + threadIdx.x;
    int v = (i < N_NODES) ? ((cnt[i] + 7) & ~7) : 0;
    sdata[threadIdx.x] = v;
    __syncthreads();
    for (int off = 1; off < 256; off <<= 1) {
        int tmp = (threadIdx.x >= off) ? sdata[threadIdx.x - off] : 0;
        __syncthreads();
        sdata[threadIdx.x] += tmp;
        __syncthreads();
    }
    if (i < N_NODES) rowptr[i] = boff[blockIdx.x] + sdata[threadIdx.x] - v;
}

// csr: src index only (ushort). Real entries [rowptr[d], rowptr[d]+cnt[d]).
__global__ void fill_kernel(const int* __restrict__ ei, const int* __restrict__ rowptr,
                            int* __restrict__ cursor, unsigned short* __restrict__ csr) {
    int j = blockIdx.x * blockDim.x + threadIdx.x;
    if (j >= N_EDGES) return;
    int s = ei[j], d = ei[N_EDGES + j];
    int pos = rowptr[d] + atomicAdd(&cursor[d], 1);
    csr[pos] = (unsigned short)s;
}

// fill pad slots [cnt, (cnt+7)&~7) with the dummy node index (zeroed record)
__global__ void pad_kernel(const int* __restrict__ cnt, const int* __restrict__ rowptr,
                           unsigned short* __restrict__ csr) {
    int v = blockIdx.x * 256 + threadIdx.x;
    if (v >= N_NODES) return;
    int c = cnt[v], cp = (c + 7) & ~7, base = rowptr[v];
    for (int j = c; j < cp; ++j) csr[base + j] = (unsigned short)N_NODES;
}

// repack conv_w into B-fragment order (fp16), zero ws accumulators, zero the
// 8 dummy node records in hwh2.
__global__ void wpack_zero_kernel(const float* __restrict__ W, _Float16* __restrict__ wpack,
                                  float* __restrict__ zreg, _Float16* __restrict__ hwh2) {
    int idx = blockIdx.x * 256 + threadIdx.x;
    if (idx < 4 * 4096) {
        int e = idx & 4095;
        int j = e & 7;
        int lane = (e >> 3) & 63;
        int ntkh = e >> 9;
        int kh = ntkh >> 2, nt = ntkh & 3;
        int m = lane & 15, quad = lane >> 4;
        wpack[idx] = (_Float16)W[(idx >> 12) * 4096 + (kh * 32 + quad * 8 + j) * 64 + nt * 16 + m];
    }
    if (idx < 256) {
        hwh2[(size_t)(idx >> 5) * PSTRIDE + (size_t)N_NODES * 32 + (idx & 31)] = (_Float16)0.0f;
    }
    for (int i = idx; i < ZERO_FLOATS; i += gridDim.x * 256) zreg[i] = 0.0f;
}

// reduce 64 BN slices + gamma/beta -> bnss = {scale[64], shift[64]} (once/layer)
__global__ void bn_reduce(const float* __restrict__ bn, const float* __restrict__ gamma,
                          const float* __restrict__ beta, float* __restrict__ bnss) {
    int f = threadIdx.x;
    if (f >= 64) return;
    float su = 0.0f, sq = 0.0f;
    for (int s = 0; s < BN_SLICES; ++s) {
        su += bn[s * 128 + f];
        sq += bn[s * 128 + 64 + f];
    }
    const float inv_n = 1.0f / (float)NTOT;
    float mu = su * inv_n;
    float var = sq * inv_n - mu * mu;
    float sc = gamma[f] * rsqrtf(var + BN_EPS);
    bnss[f] = sc;
    bnss[64 + f] = beta[f] - mu * sc;
}

// ---------------- fused GEMM (MFMA, packed W) ----------------
// Writes hwh2[part][v][32] with dinv[v] folded in (part = p*2 + feature_half).
template <int LAYER0>
__global__ __launch_bounds__(256) void gemm_fused(const void* __restrict__ srcv,
        const int* __restrict__ mask, const float* __restrict__ bnss,
        const int* __restrict__ batch, const _Float16* __restrict__ wpack,
        const float* __restrict__ dinv, _Float16* __restrict__ hwh,
        float* __restrict__ pooled) {
    __shared__ _Float16 sAh[64 * SAH_STRIDE];
    __shared__ _Float16 sC[64 * SC_STRIDE];
    int tid = threadIdx.x;
    size_t rowbase = (size_t)blockIdx.x * 64;
    int lane = tid & 63;
    int wv = tid >> 6;
    // batch values for this wave's 16 pooled rows: wave-uniform scalar loads,
    // issued up-front so latency hides under A-staging + MFMA.
    int bg[16];
#pragma unroll
    for (int rr = 0; rr < 16; ++rr)
        bg[rr] = batch[(int)((rowbase + wv * 16 + rr) % N_NODES)];
    // B frags: coalesced f16x8 loads from packed W (16 KB, L2-hot)
    const f16x8* wp = (const f16x8*)wpack;
    f16x8 bfrag[2][4];
#pragma unroll
    for (int kh = 0; kh < 2; ++kh)
#pragma unroll
        for (int nt = 0; nt < 4; ++nt)
            bfrag[kh][nt] = wp[(kh * 4 + nt) * 64 + lane];
    // A staging (fp16): thread -> (row r0 + it*16, features f4..f4+3)
    int r0 = tid >> 4;
    int f4l = (tid & 15) * 4;
    float4 sc4, sh4;
    if (!LAYER0) {
        sc4 = *(const float4*)&bnss[f4l];
        sh4 = *(const float4*)&bnss[64 + f4l];
    }
#pragma unroll
    for (int it = 0; it < 4; ++it) {
        int r = r0 + it * 16;
        int grow = (int)rowbase + r;
        float4 val;
        if (LAYER0) {
            const float* src = (const float*)srcv;
            int p = grow / N_NODES, v = grow - p * N_NODES;
            if (mask[p * N_NODES + v]) {
                val = make_float4(0.f, 0.f, 0.f, 0.f);
            } else {
                val = *(const float4*)&src[(size_t)v * HDIM + f4l];
            }
        } else {
            const _Float16* src = (const _Float16*)srcv;
            half4 hv = *(const half4*)&src[(size_t)grow * HDIM + f4l];
            val.x = fmaxf((float)hv.x * sc4.x + sh4.x, 0.0f);
            val.y = fmaxf((float)hv.y * sc4.y + sh4.y, 0.0f);
            val.z = fmaxf((float)hv.z * sc4.z + sh4.z, 0.0f);
            val.w = fmaxf((float)hv.w * sc4.w + sh4.w, 0.0f);
        }
        half4 hv4 = {(_Float16)val.x, (_Float16)val.y, (_Float16)val.z, (_Float16)val.w};
        *(half4*)&sAh[r * SAH_STRIDE + f4l] = hv4;
    }
    __syncthreads();
    // MFMA: wave wv owns rows wv*16..wv*16+15; A-frag = one ds_read_b128 per kh
    int m = lane & 15;
    int quad = lane >> 4;
    f32x4 acc4[4];
#pragma unroll
    for (int nt = 0; nt < 4; ++nt) acc4[nt] = (f32x4){0.f, 0.f, 0.f, 0.f};
#pragma unroll
    for (int kh = 0; kh < 2; ++kh) {
        f16x8 a = *(const f16x8*)&sAh[(wv * 16 + m) * SAH_STRIDE + kh * 32 + quad * 8];
#pragma unroll
        for (int nt = 0; nt < 4; ++nt)
            acc4[nt] = __builtin_amdgcn_mfma_f32_16x16x32_f16(a, bfrag[kh][nt], acc4[nt], 0, 0, 0);
    }
    // C frag layout: col = nt*16+m, row(in 16-tile) = quad*4+reg -> stage to sC
    // with dinv[v] folded in (gather consumes dinv_s-scaled messages).
#pragma unroll
    for (int reg = 0; reg < 4; ++reg) {
        int crow = wv * 16 + quad * 4 + reg;
        int growc = (int)rowbase + crow;
        int vc = growc % N_NODES;
        float dsc = dinv[vc];
#pragma unroll
        for (int nt = 0; nt < 4; ++nt)
            sC[crow * SC_STRIDE + nt * 16 + m] = (_Float16)(acc4[nt][reg] * dsc);
    }
    __syncthreads();
    // coalesced store first: thread -> row tid>>2, 16B chunk (tid&3) into both
    // feature-half partitions (64B node granules, contiguous per part).
    {
        int r = tid >> 2, c = tid & 3;
        int grow = (int)rowbase + r;
        int p = grow / N_NODES, v = grow - p * N_NODES;
        _Float16* dst0 = &hwh[(size_t)(p * 2 + 0) * PSTRIDE + (size_t)v * 32];
        _Float16* dst1 = &hwh[(size_t)(p * 2 + 1) * PSTRIDE + (size_t)v * 32];
        *(f16x8*)&dst0[c * 8] = *(f16x8*)&sC[r * SC_STRIDE + c * 8];
        *(f16x8*)&dst1[c * 8] = *(f16x8*)&sC[r * SC_STRIDE + (c + 4) * 8];
    }
    // pooling last (overlaps store drain): wave pools its 16 rows from sAh
    {
        int f = lane;
        int curg = -1;
        float acc = 0.0f;
#pragma unroll
        for (int rr = 0; rr < 16; ++rr) {
            int g = bg[rr];
            if (g != curg) {
                if (curg >= 0) atomicAdd(&pooled[curg * HDIM + f], acc * (1.0f / P_PERT));
                curg = g;
                acc = 0.0f;
            }
            acc += (float)sAh[(wv * 16 + rr) * SAH_STRIDE + f];
        }
        atomicAdd(&pooled[curg * HDIM + f], acc * (1.0f / P_PERT));
    }
}

// ---------------- XCD-partitioned gather, 16 nodes x 4 flanes ----------------
// part = blockIdx&7 -> XCD. Each lane owns 16 B (f16x8) of its node's 64 B part
// record. 8 edges/iter: prefetched u16x8 csr index + 8 b128 message loads ->
// packed-fp16 tree-sum -> one f32 fold. Branchless via x8 padding (dummy node).
__global__ __launch_bounds__(256) void gather_bn(const _Float16* __restrict__ hwh2,
        const int* __restrict__ rowptr, const unsigned short* __restrict__ csr,
        const float* __restrict__ dinv, const float* __restrict__ b,
        _Float16* __restrict__ h, float* __restrict__ bn) {
    __shared__ float lsum[4][4][8];
    __shared__ float lssq[4][4][8];
    int tid = threadIdx.x;
    int lane = tid & 63;
    int wv = tid >> 6;
    int part = blockIdx.x & 7;          // -> XCD
    int grp = blockIdx.x >> 3;          // node group (64 nodes per block)
    int p = part >> 1, fh = part & 1;
    int n16 = lane >> 2;                // node within wave (0..15)
    int f16 = lane & 3;                 // 16B chunk within 64B part record
    int v = grp * 64 + wv * 16 + n16;
    bool valid = v < N_NODES;
    int vv = valid ? v : N_NODES;       // dummy row: safe zero reads
    int kb = 0, ke = 0;
    float di = 0.0f;
    if (valid) { kb = rowptr[v]; ke = rowptr[v + 1]; di = dinv[v]; }
    const _Float16* lsrc = hwh2 + (size_t)part * PSTRIDE + f16 * 8;  // lane base
    f16x8 sv = *(const f16x8*)&lsrc[(size_t)vv * 32];   // self term
    float acc[8];
#pragma unroll
    for (int j = 0; j < 8; ++j) acc[j] = 0.0f;
    u16x8 ci = {};
    if (kb < ke) ci = *(const u16x8*)&csr[kb];          // prefetched indices
    for (int k = kb; k < ke; k += 8) {
        u16x8 cin = {};
        if (k + 8 < ke) cin = *(const u16x8*)&csr[k + 8];   // next-iter prefetch
        f16x8 m0 = *(const f16x8*)&lsrc[(size_t)ci[0] * 32];
        f16x8 m1 = *(const f16x8*)&lsrc[(size_t)ci[1] * 32];
        f16x8 m2 = *(const f16x8*)&lsrc[(size_t)ci[2] * 32];
        f16x8 m3 = *(const f16x8*)&lsrc[(size_t)ci[3] * 32];
        f16x8 m4 = *(const f16x8*)&lsrc[(size_t)ci[4] * 32];
        f16x8 m5 = *(const f16x8*)&lsrc[(size_t)ci[5] * 32];
        f16x8 m6 = *(const f16x8*)&lsrc[(size_t)ci[6] * 32];
        f16x8 m7 = *(const f16x8*)&lsrc[(size_t)ci[7] * 32];
        // packed-fp16 tree (v_pk_add_f16), 3 rounding levels, then f32 fold
        f16x8 s = ((m0 + m1) + (m2 + m3)) + ((m4 + m5) + (m6 + m7));
#pragma unroll
        for (int j = 0; j < 8; ++j) acc[j] += (float)s[j];
        ci = cin;
    }
    float hv[8], qv[8];
    float4 b0 = *(const float4*)&b[fh * 32 + f16 * 8];
    float4 b1 = *(const float4*)&b[fh * 32 + f16 * 8 + 4];
    float bb[8] = {b0.x, b0.y, b0.z, b0.w, b1.x, b1.y, b1.z, b1.w};
#pragma unroll
    for (int j = 0; j < 8; ++j) {
        float x = valid ? fmaf(di, acc[j] + (float)sv[j], bb[j]) : 0.0f;
        hv[j] = x;
        qv[j] = x * x;
    }
    if (valid) {
        f16x8 hh;
#pragma unroll
        for (int j = 0; j < 8; ++j) hh[j] = (_Float16)hv[j];
        // nontemporal: consumed only by the next dispatch; keep hwh2 L2-resident
        __builtin_nontemporal_store(hh,
            (f16x8*)&h[((size_t)p * N_NODES + (size_t)v) * HDIM + fh * 32 + f16 * 8]);
    }
    // reduce across the 16 nodes (lane bits 2..5); 16B chunk preserved
#pragma unroll
    for (int d = 4; d <= 32; d <<= 1) {
#pragma unroll
        for (int j = 0; j < 8; ++j) {
            hv[j] += __shfl_xor(hv[j], d);
            qv[j] += __shfl_xor(qv[j], d);
        }
    }
    if (lane < 4) {
#pragma unroll
        for (int j = 0; j < 8; ++j) {
            lsum[wv][f16][j] = hv[j];
            lssq[wv][f16][j] = qv[j];
        }
    }
    __syncthreads();
    if (tid < 32) {
        int q = tid >> 3, j = tid & 7;
        float s = lsum[0][q][j] + lsum[1][q][j] + lsum[2][q][j] + lsum[3][q][j];
        float qq = lssq[0][q][j] + lssq[1][q][j] + lssq[2][q][j] + lssq[3][q][j];
        float* bns = bn + (blockIdx.x & (BN_SLICES - 1)) * 128;
        int f = fh * 32 + q * 8 + j;
        atomicAdd(&bns[f], s);
        atomicAdd(&bns[64 + f], qq);
    }
}

// pool of last layer's activation using precomputed scale/shift
__global__ void final_pool(const _Float16* __restrict__ h, const float* __restrict__ bnss,
                           const int* __restrict__ batch, float* __restrict__ pooled) {
    int t = blockIdx.x * blockDim.x + threadIdx.x;
    if (t >= N_NODES * HDIM) return;
    int v = t >> 6, f = t & 63;
    float sc = bnss[f], sh = bnss[64 + f];
    float s = 0.0f;
#pragma unroll
    for (int p = 0; p < P_PERT; ++p) {
        size_t idx = ((size_t)(p * N_NODES + v)) * HDIM + f;
        s += fmaxf((float)h[idx] * sc + sh, 0.0f);
    }
    atomicAdd(&pooled[batch[v] * HDIM + f], s * (1.0f / P_PERT));
}

// y[g][c] = sum_i pooled_i[g] @ fc_w[i][:,c] + fc_b[i][c]; out = log_softmax(y)
__global__ void head_kernel(const float* __restrict__ pooled, const float* __restrict__ fcw,
                            const float* __restrict__ fcb, float* __restrict__ out) {
    int g = blockIdx.x;
    __shared__ float y[NCLASS];
    __shared__ float lse;
    int c = threadIdx.x;
    if (c < NCLASS) {
        float acc = 0.0f;
        for (int i = 0; i < 5; ++i) {
            acc += fcb[i * NCLASS + c];
            const float* pr = &pooled[((size_t)i * NGRAPH + g) * HDIM];
            const float* w = &fcw[i * HDIM * NCLASS + c];
            for (int k = 0; k < HDIM; ++k) acc += pr[k] * w[k * NCLASS];
        }
        y[c] = acc;
    }
    __syncthreads();
    if (threadIdx.x == 0) {
        float m = y[0];
        for (int i = 1; i < NCLASS; ++i) m = fmaxf(m, y[i]);
        float s = 0.0f;
        for (int i = 0; i < NCLASS; ++i) s += expf(y[i] - m);
        lse = m + logf(s);
    }
    __syncthreads();
    if (c < NCLASS) out[g * NCLASS + c] = y[c] - lse;
}

// ---------------- launch ----------------
extern "C" void kernel_launch(void* const* d_in, const int* in_sizes, int n_in,
                              void* d_out, int out_size, void* d_ws, size_t ws_size,
                              hipStream_t stream) {
    const float* x      = (const float*)d_in[0];
    const int*   ei     = (const int*)d_in[1];
    const int*   batch  = (const int*)d_in[2];
    const int*   mask   = (const int*)d_in[3];
    const float* conv_w = (const float*)d_in[4];
    const float* conv_b = (const float*)d_in[5];
    const float* gamma  = (const float*)d_in[6];
    const float* beta   = (const float*)d_in[7];
    const float* fcw    = (const float*)d_in[8];
    const float* fcb    = (const float*)d_in[9];
    float* out = (float*)d_out;

    char* ws = (char*)d_ws;
    // --- contiguous zeroed region [0, 1188480) (ZERO_FLOATS*4) ---
    int*      cnt     = (int*)(ws + 0);             // N ints
    int*      cursor  = (int*)(ws + 200000);        // N ints
    float*    pooled  = (float*)(ws + 400000);      // 5*512*64 f -> ends 1055360
    float*    bn      = (float*)(ws + 1055360);     // 4*64*128 f -> ends 1186432
    float*    bnss    = (float*)(ws + 1186432);     // 4*128 f -> ends 1188480
    // --- rest; h/hwh 4096-aligned, csr 16B-aligned ---
    int*      rowptr  = (int*)(ws + 1188480);       // N+1 ints -> ends 1388484
    float*    dinv    = (float*)(ws + 1388484);     // N f -> ends 1588484
    unsigned short* csr = (unsigned short*)(ws + 1588496); // 1.2M u16 (padded) -> ends 3988496
    _Float16* h       = (_Float16*)(ws + 3989504);  // 4096-aligned; 25.6 MB
    _Float16* hwh     = (_Float16*)(ws + 29589504); // 4096-aligned; 8 x 50001-node parts
    int*      bsum    = (int*)(ws + 55190016);      // 256 ints
    int*      boff    = (int*)(ws + 55191040);      // 256 ints
    _Float16* wpack   = (_Float16*)(ws + 55192064); // 4*4096 fp16 (32 KB)

    wpack_zero_kernel<<<512, 256, 0, stream>>>(conv_w, wpack, (float*)ws, hwh);
    count_kernel<<<(N_EDGES + 255) / 256, 256, 0, stream>>>(ei, cnt);
    scan_reduce<<<SCAN_BLOCKS, 256, 0, stream>>>(cnt, bsum, dinv);
    scan_tops<<<1, 256, 0, stream>>>(bsum, boff, rowptr);
    scan_write<<<SCAN_BLOCKS, 256, 0, stream>>>(cnt, boff, rowptr);
    fill_kernel<<<(N_EDGES + 255) / 256, 256, 0, stream>>>(ei, rowptr, cursor, csr);
    pad_kernel<<<SCAN_BLOCKS, 256, 0, stream>>>(cnt, rowptr, csr);

    for (int i = 0; i < 4; ++i) {
        float* bni = bn + i * BN_SLICES * 128;
        if (i == 0)
            gemm_fused<1><<<NTOT / 64, 256, 0, stream>>>(x, mask, nullptr,
                                                         batch, wpack, dinv, hwh, pooled);
        else
            gemm_fused<0><<<NTOT / 64, 256, 0, stream>>>(h, nullptr, bnss + (i - 1) * 128,
                                                         batch, wpack + (size_t)i * 4096,
                                                         dinv, hwh,
                                                         pooled + (size_t)i * NGRAPH * HDIM);
        gather_bn<<<GATHER_BLOCKS, 256, 0, stream>>>(hwh, rowptr, csr, dinv,
                                                     conv_b + i * HDIM, h, bni);
        bn_reduce<<<1, 64, 0, stream>>>(bni, gamma + i * HDIM, beta + i * HDIM,
                                        bnss + i * 128);
    }
    final_pool<<<(N_NODES * HDIM + 255) / 256, 256, 0, stream>>>(
        h, bnss + 3 * 128, batch, pooled + (size_t)4 * NGRAPH * HDIM);
    head_kernel<<<NGRAPH, 64, 0, stream>>>(pooled, fcw, fcb, out);
}

// Round 13
// 399.916 us; speedup vs baseline: 1.6723x; 1.1041x over previous
//
#include <hip/hip_runtime.h>

// ---------------- problem constants ----------------
#define N_NODES 50000
#define N_EDGES 800000
#define P_PERT  4
#define NTOT    (P_PERT * N_NODES)   // 200000
#define HDIM    64
#define NGRAPH  512
#define NCLASS  10
#define BN_EPS  1e-5f
#define SCAN_BLOCKS ((N_NODES + 255) / 256)   // 196
#define BN_SLICES 64
#define SAH_STRIDE 72  // halves; 144B rows, 16B-aligned frag reads, 2-way bank alias max
#define SC_STRIDE 72   // halves
#define ZERO_FLOATS 297120          // 1188480 bytes zeroed at ws start
#define PSTRIDE ((size_t)(N_NODES + 1) * 32)   // halves per part (+1 zeroed dummy node)
#define GATHER_BLOCKS (((N_NODES + 63) / 64) * 8)  // 782 groups x 8 parts = 6256

typedef _Float16 half4 __attribute__((ext_vector_type(4)));
typedef _Float16 f16x8 __attribute__((ext_vector_type(8)));
typedef float    f32x4 __attribute__((ext_vector_type(4)));
typedef unsigned short u16x8 __attribute__((ext_vector_type(8)));

// R18 VERIFIED R3: 8 XCD-resident hwh partitions, FETCH 188 -> 20.6 MB.
// R19 VERIFIED R5: node-per-lane padded walk 105 -> 57.6 us.
// R20 VERIFIED R11: 16 nodes x 4 flanes, pk_add_f16 tree, csr prefetch ->
// gather out of top-5 (<44.5 us); total 492.5 -> 441.5 us.
// R21 (this round): fill_kernel is now top dispatch (45 us, VALU 0.5%,
// WRITE 49.5 MB scattered): (1) count_kernel records atomic return as slot[j]
// -> fill needs no atomic; (2) bn_reduce widened 64 -> 512 threads;
// (3) final_pool run-length pools 4 nodes/thread before atomics (3.2M -> .85M).
// gemm/gather untouched as controls.
// R17 lesson: NO device-scope fences in the gather (kills per-XCD L2).
// R13 lesson: 64B node granules, 4096-aligned bases.

// ---------------- CSR build ----------------

// counts AND records each edge's slot within its dst list (atomic return val)
__global__ void count_kernel(const int* __restrict__ ei, int* __restrict__ cnt,
                             int* __restrict__ slot) {
    int j = blockIdx.x * blockDim.x + threadIdx.x;
    if (j >= N_EDGES) return;
    slot[j] = atomicAdd(&cnt[ei[N_EDGES + j]], 1);
}

// scans PADDED counts ((cnt+7)&~7) so every node's list is a multiple of 8;
// dinv still uses the raw count.
__global__ void scan_reduce(const int* __restrict__ cnt, int* __restrict__ bsum,
                            float* __restrict__ dinv) {
    __shared__ int sdata[256];
    int i = blockIdx.x * 256 + threadIdx.x;
    int v = (i < N_NODES) ? cnt[i] : 0;
    if (i < N_NODES) dinv[i] = rsqrtf((float)v + 1.0f);
    sdata[threadIdx.x] = (v + 7) & ~7;
    __syncthreads();
    for (int off = 128; off > 0; off >>= 1) {
        if (threadIdx.x < off) sdata[threadIdx.x] += sdata[threadIdx.x + off];
        __syncthreads();
    }
    if (threadIdx.x == 0) bsum[blockIdx.x] = sdata[0];
}

__global__ void scan_tops(const int* __restrict__ bsum, int* __restrict__ boff,
                          int* __restrict__ rowptr) {
    __shared__ int sdata[256];
    int t = threadIdx.x;
    int v = (t < SCAN_BLOCKS) ? bsum[t] : 0;
    sdata[t] = v;
    __syncthreads();
    for (int off = 1; off < 256; off <<= 1) {
        int tmp = (t >= off) ? sdata[t - off] : 0;
        __syncthreads();
        sdata[t] += tmp;
        __syncthreads();
    }
    if (t < SCAN_BLOCKS) boff[t] = sdata[t] - v;
    if (t == 255) rowptr[N_NODES] = sdata[255];
}

__global__ void scan_write(const int* __restrict__ cnt, const int* __restrict__ boff,
                           int* __restrict__ rowptr) {
    __shared__ int sdata[256];
    int i = blockIdx.x * 256 + threadIdx.x;
    int v = (i < N_NODES) ? ((cnt[i] + 7) & ~7) : 0;
    sdata[threadIdx.x] = v;
    __syncthreads();
    for (int off = 1; off < 256; off <<= 1) {
        int tmp = (threadIdx.x >= off) ? sdata[threadIdx.x - off] : 0;
        __syncthreads();
        sdata[threadIdx.x] += tmp;
        __syncthreads();
    }
    if (i < N_NODES) rowptr[i] = boff[blockIdx.x] + sdata[threadIdx.x] - v;
}

// csr: src index only (ushort). Atomic-free: position from precomputed slot.
__global__ void fill_kernel(const int* __restrict__ ei, const int* __restrict__ rowptr,
                            const int* __restrict__ slot, unsigned short* __restrict__ csr) {
    int j = blockIdx.x * blockDim.x + threadIdx.x;
    if (j >= N_EDGES) return;
    int s = ei[j], d = ei[N_EDGES + j];
    csr[rowptr[d] + slot[j]] = (unsigned short)s;
}

// fill pad slots [cnt, (cnt+7)&~7) with the dummy node index (zeroed record)
__global__ void pad_kernel(const int* __restrict__ cnt, const int* __restrict__ rowptr,
                           unsigned short* __restrict__ csr) {
    int v = blockIdx.x * 256 + threadIdx.x;
    if (v >= N_NODES) return;
    int c = cnt[v], cp = (c + 7) & ~7, base = rowptr[v];
    for (int j = c; j < cp; ++j) csr[base + j] = (unsigned short)N_NODES;
}

// repack conv_w into B-fragment order (fp16), zero ws accumulators, zero the
// 8 dummy node records in hwh2.
__global__ void wpack_zero_kernel(const float* __restrict__ W, _Float16* __restrict__ wpack,
                                  float* __restrict__ zreg, _Float16* __restrict__ hwh2) {
    int idx = blockIdx.x * 256 + threadIdx.x;
    if (idx < 4 * 4096) {
        int e = idx & 4095;
        int j = e & 7;
        int lane = (e >> 3) & 63;
        int ntkh = e >> 9;
        int kh = ntkh >> 2, nt = ntkh & 3;
        int m = lane & 15, quad = lane >> 4;
        wpack[idx] = (_Float16)W[(idx >> 12) * 4096 + (kh * 32 + quad * 8 + j) * 64 + nt * 16 + m];
    }
    if (idx < 256) {
        hwh2[(size_t)(idx >> 5) * PSTRIDE + (size_t)N_NODES * 32 + (idx & 31)] = (_Float16)0.0f;
    }
    for (int i = idx; i < ZERO_FLOATS; i += gridDim.x * 256) zreg[i] = 0.0f;
}

// reduce 64 BN slices + gamma/beta -> bnss. 512 threads: 4 slice-groups x 128
// cols (su:0-63, sq:64-127), LDS combine, 16 serial loads/thread (was 64).
__global__ void bn_reduce(const float* __restrict__ bn, const float* __restrict__ gamma,
                          const float* __restrict__ beta, float* __restrict__ bnss) {
    __shared__ float part[4][128];
    __shared__ float tot[128];
    int t = threadIdx.x;
    int f = t & 127, q = t >> 7;
    float s = 0.0f;
#pragma unroll
    for (int i = 0; i < 16; ++i) s += bn[(q * 16 + i) * 128 + f];
    part[q][f] = s;
    __syncthreads();
    if (t < 128) tot[t] = part[0][t] + part[1][t] + part[2][t] + part[3][t];
    __syncthreads();
    if (t < 64) {
        float su = tot[t], sq = tot[64 + t];
        const float inv_n = 1.0f / (float)NTOT;
        float mu = su * inv_n;
        float var = sq * inv_n - mu * mu;
        float sc = gamma[t] * rsqrtf(var + BN_EPS);
        bnss[t] = sc;
        bnss[64 + t] = beta[t] - mu * sc;
    }
}

// ---------------- fused GEMM (MFMA, packed W) ----------------
// Writes hwh2[part][v][32] with dinv[v] folded in (part = p*2 + feature_half).
template <int LAYER0>
__global__ __launch_bounds__(256) void gemm_fused(const void* __restrict__ srcv,
        const int* __restrict__ mask, const float* __restrict__ bnss,
        const int* __restrict__ batch, const _Float16* __restrict__ wpack,
        const float* __restrict__ dinv, _Float16* __restrict__ hwh,
        float* __restrict__ pooled) {
    __shared__ _Float16 sAh[64 * SAH_STRIDE];
    __shared__ _Float16 sC[64 * SC_STRIDE];
    int tid = threadIdx.x;
    size_t rowbase = (size_t)blockIdx.x * 64;
    int lane = tid & 63;
    int wv = tid >> 6;
    // batch values for this wave's 16 pooled rows: wave-uniform scalar loads,
    // issued up-front so latency hides under A-staging + MFMA.
    int bg[16];
#pragma unroll
    for (int rr = 0; rr < 16; ++rr)
        bg[rr] = batch[(int)((rowbase + wv * 16 + rr) % N_NODES)];
    // B frags: coalesced f16x8 loads from packed W (16 KB, L2-hot)
    const f16x8* wp = (const f16x8*)wpack;
    f16x8 bfrag[2][4];
#pragma unroll
    for (int kh = 0; kh < 2; ++kh)
#pragma unroll
        for (int nt = 0; nt < 4; ++nt)
            bfrag[kh][nt] = wp[(kh * 4 + nt) * 64 + lane];
    // A staging (fp16): thread -> (row r0 + it*16, features f4..f4+3)
    int r0 = tid >> 4;
    int f4l = (tid & 15) * 4;
    float4 sc4, sh4;
    if (!LAYER0) {
        sc4 = *(const float4*)&bnss[f4l];
        sh4 = *(const float4*)&bnss[64 + f4l];
    }
#pragma unroll
    for (int it = 0; it < 4; ++it) {
        int r = r0 + it * 16;
        int grow = (int)rowbase + r;
        float4 val;
        if (LAYER0) {
            const float* src = (const float*)srcv;
            int p = grow / N_NODES, v = grow - p * N_NODES;
            if (mask[p * N_NODES + v]) {
                val = make_float4(0.f, 0.f, 0.f, 0.f);
            } else {
                val = *(const float4*)&src[(size_t)v * HDIM + f4l];
            }
        } else {
            const _Float16* src = (const _Float16*)srcv;
            half4 hv = *(const half4*)&src[(size_t)grow * HDIM + f4l];
            val.x = fmaxf((float)hv.x * sc4.x + sh4.x, 0.0f);
            val.y = fmaxf((float)hv.y * sc4.y + sh4.y, 0.0f);
            val.z = fmaxf((float)hv.z * sc4.z + sh4.z, 0.0f);
            val.w = fmaxf((float)hv.w * sc4.w + sh4.w, 0.0f);
        }
        half4 hv4 = {(_Float16)val.x, (_Float16)val.y, (_Float16)val.z, (_Float16)val.w};
        *(half4*)&sAh[r * SAH_STRIDE + f4l] = hv4;
    }
    __syncthreads();
    // MFMA: wave wv owns rows wv*16..wv*16+15; A-frag = one ds_read_b128 per kh
    int m = lane & 15;
    int quad = lane >> 4;
    f32x4 acc4[4];
#pragma unroll
    for (int nt = 0; nt < 4; ++nt) acc4[nt] = (f32x4){0.f, 0.f, 0.f, 0.f};
#pragma unroll
    for (int kh = 0; kh < 2; ++kh) {
        f16x8 a = *(const f16x8*)&sAh[(wv * 16 + m) * SAH_STRIDE + kh * 32 + quad * 8];
#pragma unroll
        for (int nt = 0; nt < 4; ++nt)
            acc4[nt] = __builtin_amdgcn_mfma_f32_16x16x32_f16(a, bfrag[kh][nt], acc4[nt], 0, 0, 0);
    }
    // C frag layout: col = nt*16+m, row(in 16-tile) = quad*4+reg -> stage to sC
    // with dinv[v] folded in (gather consumes dinv_s-scaled messages).
#pragma unroll
    for (int reg = 0; reg < 4; ++reg) {
        int crow = wv * 16 + quad * 4 + reg;
        int growc = (int)rowbase + crow;
        int vc = growc % N_NODES;
        float dsc = dinv[vc];
#pragma unroll
        for (int nt = 0; nt < 4; ++nt)
            sC[crow * SC_STRIDE + nt * 16 + m] = (_Float16)(acc4[nt][reg] * dsc);
    }
    __syncthreads();
    // coalesced store first: thread -> row tid>>2, 16B chunk (tid&3) into both
    // feature-half partitions (64B node granules, contiguous per part).
    {
        int r = tid >> 2, c = tid & 3;
        int grow = (int)rowbase + r;
        int p = grow / N_NODES, v = grow - p * N_NODES;
        _Float16* dst0 = &hwh[(size_t)(p * 2 + 0) * PSTRIDE + (size_t)v * 32];
        _Float16* dst1 = &hwh[(size_t)(p * 2 + 1) * PSTRIDE + (size_t)v * 32];
        *(f16x8*)&dst0[c * 8] = *(f16x8*)&sC[r * SC_STRIDE + c * 8];
        *(f16x8*)&dst1[c * 8] = *(f16x8*)&sC[r * SC_STRIDE + (c + 4) * 8];
    }
    // pooling last (overlaps store drain): wave pools its 16 rows from sAh
    {
        int f = lane;
        int curg = -1;
        float acc = 0.0f;
#pragma unroll
        for (int rr = 0; rr < 16; ++rr) {
            int g = bg[rr];
            if (g != curg) {
                if (curg >= 0) atomicAdd(&pooled[curg * HDIM + f], acc * (1.0f / P_PERT));
                curg = g;
                acc = 0.0f;
            }
            acc += (float)sAh[(wv * 16 + rr) * SAH_STRIDE + f];
        }
        atomicAdd(&pooled[curg * HDIM + f], acc * (1.0f / P_PERT));
    }
}

// ---------------- XCD-partitioned gather, 16 nodes x 4 flanes ----------------
// part = blockIdx&7 -> XCD. Each lane owns 16 B (f16x8) of its node's 64 B part
// record. 8 edges/iter: prefetched u16x8 csr index + 8 b128 message loads ->
// packed-fp16 tree-sum -> one f32 fold. Branchless via x8 padding (dummy node).
__global__ __launch_bounds__(256) void gather_bn(const _Float16* __restrict__ hwh2,
        const int* __restrict__ rowptr, const unsigned short* __restrict__ csr,
        const float* __restrict__ dinv, const float* __restrict__ b,
        _Float16* __restrict__ h, float* __restrict__ bn) {
    __shared__ float lsum[4][4][8];
    __shared__ float lssq[4][4][8];
    int tid = threadIdx.x;
    int lane = tid & 63;
    int wv = tid >> 6;
    int part = blockIdx.x & 7;          // -> XCD
    int grp = blockIdx.x >> 3;          // node group (64 nodes per block)
    int p = part >> 1, fh = part & 1;
    int n16 = lane >> 2;                // node within wave (0..15)
    int f16 = lane & 3;                 // 16B chunk within 64B part record
    int v = grp * 64 + wv * 16 + n16;
    bool valid = v < N_NODES;
    int vv = valid ? v : N_NODES;       // dummy row: safe zero reads
    int kb = 0, ke = 0;
    float di = 0.0f;
    if (valid) { kb = rowptr[v]; ke = rowptr[v + 1]; di = dinv[v]; }
    const _Float16* lsrc = hwh2 + (size_t)part * PSTRIDE + f16 * 8;  // lane base
    f16x8 sv = *(const f16x8*)&lsrc[(size_t)vv * 32];   // self term
    float acc[8];
#pragma unroll
    for (int j = 0; j < 8; ++j) acc[j] = 0.0f;
    u16x8 ci = {};
    if (kb < ke) ci = *(const u16x8*)&csr[kb];          // prefetched indices
    for (int k = kb; k < ke; k += 8) {
        u16x8 cin = {};
        if (k + 8 < ke) cin = *(const u16x8*)&csr[k + 8];   // next-iter prefetch
        f16x8 m0 = *(const f16x8*)&lsrc[(size_t)ci[0] * 32];
        f16x8 m1 = *(const f16x8*)&lsrc[(size_t)ci[1] * 32];
        f16x8 m2 = *(const f16x8*)&lsrc[(size_t)ci[2] * 32];
        f16x8 m3 = *(const f16x8*)&lsrc[(size_t)ci[3] * 32];
        f16x8 m4 = *(const f16x8*)&lsrc[(size_t)ci[4] * 32];
        f16x8 m5 = *(const f16x8*)&lsrc[(size_t)ci[5] * 32];
        f16x8 m6 = *(const f16x8*)&lsrc[(size_t)ci[6] * 32];
        f16x8 m7 = *(const f16x8*)&lsrc[(size_t)ci[7] * 32];
        // packed-fp16 tree (v_pk_add_f16), 3 rounding levels, then f32 fold
        f16x8 s = ((m0 + m1) + (m2 + m3)) + ((m4 + m5) + (m6 + m7));
#pragma unroll
        for (int j = 0; j < 8; ++j) acc[j] += (float)s[j];
        ci = cin;
    }
    float hv[8], qv[8];
    float4 b0 = *(const float4*)&b[fh * 32 + f16 * 8];
    float4 b1 = *(const float4*)&b[fh * 32 + f16 * 8 + 4];
    float bb[8] = {b0.x, b0.y, b0.z, b0.w, b1.x, b1.y, b1.z, b1.w};
#pragma unroll
    for (int j = 0; j < 8; ++j) {
        float x = valid ? fmaf(di, acc[j] + (float)sv[j], bb[j]) : 0.0f;
        hv[j] = x;
        qv[j] = x * x;
    }
    if (valid) {
        f16x8 hh;
#pragma unroll
        for (int j = 0; j < 8; ++j) hh[j] = (_Float16)hv[j];
        // nontemporal: consumed only by the next dispatch; keep hwh2 L2-resident
        __builtin_nontemporal_store(hh,
            (f16x8*)&h[((size_t)p * N_NODES + (size_t)v) * HDIM + fh * 32 + f16 * 8]);
    }
    // reduce across the 16 nodes (lane bits 2..5); 16B chunk preserved
#pragma unroll
    for (int d = 4; d <= 32; d <<= 1) {
#pragma unroll
        for (int j = 0; j < 8; ++j) {
            hv[j] += __shfl_xor(hv[j], d);
            qv[j] += __shfl_xor(qv[j], d);
        }
    }
    if (lane < 4) {
#pragma unroll
        for (int j = 0; j < 8; ++j) {
            lsum[wv][f16][j] = hv[j];
            lssq[wv][f16][j] = qv[j];
        }
    }
    __syncthreads();
    if (tid < 32) {
        int q = tid >> 3, j = tid & 7;
        float s = lsum[0][q][j] + lsum[1][q][j] + lsum[2][q][j] + lsum[3][q][j];
        float qq = lssq[0][q][j] + lssq[1][q][j] + lssq[2][q][j] + lssq[3][q][j];
        float* bns = bn + (blockIdx.x & (BN_SLICES - 1)) * 128;
        int f = fh * 32 + q * 8 + j;
        atomicAdd(&bns[f], s);
        atomicAdd(&bns[64 + f], qq);
    }
}

// pool of last layer's activation. Block = 64 f x 4 subgroups; each thread
// walks 4 consecutive (sorted-batch) nodes, run-length accumulating by graph
// before the atomic -> ~4x fewer pooled atomics.
__global__ void final_pool(const _Float16* __restrict__ h, const float* __restrict__ bnss,
                           const int* __restrict__ batch, float* __restrict__ pooled) {
    int f = threadIdx.x & 63;
    int sg = threadIdx.x >> 6;              // 0..3
    int vb = blockIdx.x * 16 + sg * 4;      // 4 nodes per thread
    float sc = bnss[f], sh = bnss[64 + f];
    int curg = -1;
    float acc = 0.0f;
#pragma unroll
    for (int i = 0; i < 4; ++i) {
        int v = vb + i;
        if (v >= N_NODES) break;
        float s = 0.0f;
#pragma unroll
        for (int p = 0; p < P_PERT; ++p) {
            size_t idx = ((size_t)(p * N_NODES + v)) * HDIM + f;
            s += fmaxf((float)h[idx] * sc + sh, 0.0f);
        }
        int g = batch[v];
        if (g != curg) {
            if (curg >= 0) atomicAdd(&pooled[curg * HDIM + f], acc * (1.0f / P_PERT));
            curg = g;
            acc = 0.0f;
        }
        acc += s;
    }
    if (curg >= 0) atomicAdd(&pooled[curg * HDIM + f], acc * (1.0f / P_PERT));
}

// y[g][c] = sum_i pooled_i[g] @ fc_w[i][:,c] + fc_b[i][c]; out = log_softmax(y)
__global__ void head_kernel(const float* __restrict__ pooled, const float* __restrict__ fcw,
                            const float* __restrict__ fcb, float* __restrict__ out) {
    int g = blockIdx.x;
    __shared__ float y[NCLASS];
    __shared__ float lse;
    int c = threadIdx.x;
    if (c < NCLASS) {
        float acc = 0.0f;
        for (int i = 0; i < 5; ++i) {
            acc += fcb[i * NCLASS + c];
            const float* pr = &pooled[((size_t)i * NGRAPH + g) * HDIM];
            const float* w = &fcw[i * HDIM * NCLASS + c];
            for (int k = 0; k < HDIM; ++k) acc += pr[k] * w[k * NCLASS];
        }
        y[c] = acc;
    }
    __syncthreads();
    if (threadIdx.x == 0) {
        float m = y[0];
        for (int i = 1; i < NCLASS; ++i) m = fmaxf(m, y[i]);
        float s = 0.0f;
        for (int i = 0; i < NCLASS; ++i) s += expf(y[i] - m);
        lse = m + logf(s);
    }
    __syncthreads();
    if (c < NCLASS) out[g * NCLASS + c] = y[c] - lse;
}

// ---------------- launch ----------------
extern "C" void kernel_launch(void* const* d_in, const int* in_sizes, int n_in,
                              void* d_out, int out_size, void* d_ws, size_t ws_size,
                              hipStream_t stream) {
    const float* x      = (const float*)d_in[0];
    const int*   ei     = (const int*)d_in[1];
    const int*   batch  = (const int*)d_in[2];
    const int*   mask   = (const int*)d_in[3];
    const float* conv_w = (const float*)d_in[4];
    const float* conv_b = (const float*)d_in[5];
    const float* gamma  = (const float*)d_in[6];
    const float* beta   = (const float*)d_in[7];
    const float* fcw    = (const float*)d_in[8];
    const float* fcb    = (const float*)d_in[9];
    float* out = (float*)d_out;

    char* ws = (char*)d_ws;
    // --- contiguous zeroed region [0, 1188480) (ZERO_FLOATS*4) ---
    int*      cnt     = (int*)(ws + 0);             // N ints
    // (ws+200000: 200000B spare, was cursor — kept zeroed for layout stability)
    float*    pooled  = (float*)(ws + 400000);      // 5*512*64 f -> ends 1055360
    float*    bn      = (float*)(ws + 1055360);     // 4*64*128 f -> ends 1186432
    float*    bnss    = (float*)(ws + 1186432);     // 4*128 f -> ends 1188480
    // --- rest; h/hwh 4096-aligned, csr 16B-aligned ---
    int*      rowptr  = (int*)(ws + 1188480);       // N+1 ints -> ends 1388484
    float*    dinv    = (float*)(ws + 1388484);     // N f -> ends 1588484
    unsigned short* csr = (unsigned short*)(ws + 1588496); // 1.2M u16 (padded) -> ends 3988496
    _Float16* h       = (_Float16*)(ws + 3989504);  // 4096-aligned; 25.6 MB
    _Float16* hwh     = (_Float16*)(ws + 29589504); // 4096-aligned; 8 x 50001-node parts
    int*      bsum    = (int*)(ws + 55190016);      // 256 ints
    int*      boff    = (int*)(ws + 55191040);      // 256 ints
    _Float16* wpack   = (_Float16*)(ws + 55192064); // 4*4096 fp16 (32 KB)
    int*      slot    = (int*)(ws + 55224832);      // E ints (3.2 MB) -> ends 58424832

    wpack_zero_kernel<<<512, 256, 0, stream>>>(conv_w, wpack, (float*)ws, hwh);
    count_kernel<<<(N_EDGES + 255) / 256, 256, 0, stream>>>(ei, cnt, slot);
    scan_reduce<<<SCAN_BLOCKS, 256, 0, stream>>>(cnt, bsum, dinv);
    scan_tops<<<1, 256, 0, stream>>>(bsum, boff, rowptr);
    scan_write<<<SCAN_BLOCKS, 256, 0, stream>>>(cnt, boff, rowptr);
    fill_kernel<<<(N_EDGES + 255) / 256, 256, 0, stream>>>(ei, rowptr, slot, csr);
    pad_kernel<<<SCAN_BLOCKS, 256, 0, stream>>>(cnt, rowptr, csr);

    for (int i = 0; i < 4; ++i) {
        float* bni = bn + i * BN_SLICES * 128;
        if (i == 0)
            gemm_fused<1><<<NTOT / 64, 256, 0, stream>>>(x, mask, nullptr,
                                                         batch, wpack, dinv, hwh, pooled);
        else
            gemm_fused<0><<<NTOT / 64, 256, 0, stream>>>(h, nullptr, bnss + (i - 1) * 128,
                                                         batch, wpack + (size_t)i * 4096,
                                                         dinv, hwh,
                                                         pooled + (size_t)i * NGRAPH * HDIM);
        gather_bn<<<GATHER_BLOCKS, 256, 0, stream>>>(hwh, rowptr, csr, dinv,
                                                     conv_b + i * HDIM, h, bni);
        bn_reduce<<<1, 512, 0, stream>>>(bni, gamma + i * HDIM, beta + i * HDIM,
                                         bnss + i * 128);
    }
    final_pool<<<(N_NODES + 15) / 16, 256, 0, stream>>>(
        h, bnss + 3 * 128, batch, pooled + (size_t)4 * NGRAPH * HDIM);
    head_kernel<<<NGRAPH, 64, 0, stream>>>(pooled, fcw, fcb, out);
}